// Round 5
// baseline (635.518 us; speedup 1.0000x reference)
//
#include <hip/hip_runtime.h>

namespace {
constexpr int kB  = 2;
constexpr int kNC = 4096;
constexpr int kNT = 1024;
constexpr int kDX = 64;
constexpr int kK  = 32;
constexpr int kNQ = kB * (kNC + kNT);            // 10240
constexpr long long kE = (long long)kNQ * kK;    // 327680
constexpr int QPW  = 4;                          // queries per wave (v3)
constexpr int TILE = 256;                        // refs per tile (v3)
constexpr int NTL  = kNC / TILE;                 // 16
// inf stand-in: must stay finite after bf16 round-trip (FLT_MAX -> bf16 inf)
constexpr float kBigFinite = 1e30f;
// d_ws float layout: xT[2][64][4096] then rn[8192]
constexpr size_t kXTF = (size_t)2 * 64 * 4096;   // 524288 floats
constexpr size_t kRNF = 8192;
constexpr size_t kWsNeed = (kXTF + kRNF) * 4;    // bytes
}

__device__ __forceinline__ void resolve_q(int gid,
    const float* x_ctx, const float* s_ctx, const float* t_ctx,
    const float* x_test, const float* s_test, const float* t_test,
    int& b, const float*& qx, const float*& qs, const float*& qt)
{
    if (gid < kB * kNC) {
        b  = gid >> 12;
        qx = x_ctx + (size_t)gid * kDX;
        qs = s_ctx + (size_t)gid * 3;
        qt = t_ctx + gid;
    } else {
        const int g2 = gid - kB * kNC;
        b  = g2 >> 10;
        qx = x_test + (size_t)g2 * kDX;
        qs = s_test + (size_t)g2 * 3;
        qt = t_test + g2;
    }
}

// Exact online insert into wave-held sorted ascending top-32 (validated r3/r4).
__device__ __forceinline__ void insert_half(unsigned long long& listKey,
    unsigned long long keyQ, int lane, int base)
{
    const unsigned long long thr = __shfl(listKey, base + 31, 64);
    unsigned long long hb = __ballot(keyQ < thr);
    while (hb) {
        const int srcl = __ffsll((unsigned long long)hb) - 1;
        hb &= hb - 1;
        const unsigned long long K = __shfl(keyQ, srcl, 64);
        const unsigned long long lt = __ballot(listKey < K);
        const unsigned int half = base ? (unsigned int)(lt >> 32)
                                       : (unsigned int)lt;
        const int pos = __popc(half) + base;
        if (pos < base + 32) {
            const unsigned long long up = __shfl_up(listKey, 1, 64);
            if (lane >= base && lane < base + 32) {
                if (lane > pos)       listKey = up;
                else if (lane == pos) listKey = K;
            }
        }
    }
}

// ---- prep: transpose x_ctx [2][4096][64] -> xT [2][64][4096] ----
__global__ __launch_bounds__(256)
void prep_transpose(const float* __restrict__ x, float* __restrict__ ws)
{
    __shared__ float tile[64][65];
    const int t = threadIdx.x, blk = blockIdx.x;     // 128 blocks x 64 refs
    const size_t base = (size_t)blk * 4096;          // 64 rows x 64 dims
    #pragma unroll
    for (int i = 0; i < 16; ++i) {
        const int n = t + 256 * i;
        tile[n >> 6][n & 63] = x[base + n];
    }
    __syncthreads();
    const int b  = blk >> 6;
    const int r0 = (blk & 63) * 64;
    float* xT = ws + (size_t)b * 64 * 4096;
    #pragma unroll
    for (int i = 0; i < 16; ++i) {
        const int n = t + 256 * i;
        const int d = n >> 6, rl = n & 63;
        xT[(size_t)d * 4096 + r0 + rl] = tile[rl][d];
    }
}

// ---- prep: rn[row] with the exact validated fmaf chain ----
__global__ __launch_bounds__(256)
void prep_rn(const float* __restrict__ x, float* __restrict__ ws)
{
    const int r = blockIdx.x * 256 + threadIdx.x;    // 0..8191
    const float4* xr = (const float4*)(x + (size_t)r * kDX);
    float rn = 0.f;
    #pragma unroll
    for (int j = 0; j < 16; ++j) {
        const float4 rv = xr[j];
        rn = fmaf(rv.x, rv.x, rn); rn = fmaf(rv.y, rv.y, rn);
        rn = fmaf(rv.z, rv.z, rn); rn = fmaf(rv.w, rv.w, rn);
    }
    ws[kXTF + r] = rn;
}

// ---- main: 1 wave per block, 4 queries per wave, dim-major coalesced refs ----
__global__ __launch_bounds__(64)
void knn_v3(const float* __restrict__ x_ctx, const float* __restrict__ s_ctx,
            const float* __restrict__ t_ctx, const unsigned char* __restrict__ mask_ctx,
            const float* __restrict__ x_test, const float* __restrict__ s_test,
            const float* __restrict__ t_test, const float* __restrict__ ws,
            float* __restrict__ out)
{
    const int lane = threadIdx.x;
    const int blk  = blockIdx.x;              // 2560
    // XCD-aware: batch 0 -> XCDs 0-3, batch 1 -> XCDs 4-7 (L2 panel locality)
    const int xcd  = blk & 7;
    const int b    = xcd >> 2;
    const int grp  = (xcd & 3) * 320 + (blk >> 3);   // 0..1279 within batch
    const int qid0 = grp * 4;                        // within-batch query id
    const int gid0 = (qid0 < kNC) ? (b * kNC + qid0)
                                  : (kB * kNC + b * kNT + (qid0 - kNC));

    // ---- per-query setup (pointers uniform: derived from blockIdx) ----
    const float* qxp[QPW];
    float qs0[QPW], qs1[QPW], qs2[QPW], qsn[QPW], qtv[QPW], qn[QPW];
    #pragma unroll
    for (int q = 0; q < QPW; ++q) {
        int bb; const float *qx, *qs, *qt;
        resolve_q(gid0 + q, x_ctx, s_ctx, t_ctx, x_test, s_test, t_test,
                  bb, qx, qs, qt);
        qxp[q] = qx;
        qs0[q] = qs[0]; qs1[q] = qs[1]; qs2[q] = qs[2]; qtv[q] = qt[0];
        qsn[q] = qs0[q]*qs0[q] + qs1[q]*qs1[q] + qs2[q]*qs2[q];
        const float ql = qx[lane];
        float s = ql * ql;
        #pragma unroll
        for (int off = 32; off > 0; off >>= 1) s += __shfl_xor(s, off, 64);
        qn[q] = s;
    }

    const float4* xT4 = (const float4*)ws + (size_t)b * (64 * 1024); // [64][1024]
    const float*  rnp = ws + kXTF + (size_t)b * kNC;
    const float*  rsp = s_ctx + (size_t)b * kNC * 3;
    const float*  rtp = t_ctx + (size_t)b * kNC;
    const unsigned char* mp = mask_ctx + (size_t)b * kNC;
    const float INF = __builtin_inff();

    unsigned long long lst01 = ~0ull, lst23 = ~0ull;  // q0/q1, q2/q3 lists

    for (int t = 0; t < NTL; ++t) {
        const int rb = t * TILE;
        const int e4 = t * 64 + lane;      // float4 index in each dim-row
        float dot[QPW][4];
        #pragma unroll
        for (int q = 0; q < QPW; ++q) {
            dot[q][0] = dot[q][1] = dot[q][2] = dot[q][3] = 0.f;
        }
        #pragma unroll
        for (int c = 0; c < 16; ++c) {
            const float4 v0 = xT4[(size_t)(4*c+0) * 1024 + e4];
            const float4 v1 = xT4[(size_t)(4*c+1) * 1024 + e4];
            const float4 v2 = xT4[(size_t)(4*c+2) * 1024 + e4];
            const float4 v3 = xT4[(size_t)(4*c+3) * 1024 + e4];
            #pragma unroll
            for (int q = 0; q < QPW; ++q) {
                const float4 qv = ((const float4*)qxp[q])[c];  // uniform -> s_load
                // dims ascending: exact same accumulation order as validated
                dot[q][0]=fmaf(qv.x,v0.x,dot[q][0]); dot[q][0]=fmaf(qv.y,v1.x,dot[q][0]);
                dot[q][0]=fmaf(qv.z,v2.x,dot[q][0]); dot[q][0]=fmaf(qv.w,v3.x,dot[q][0]);
                dot[q][1]=fmaf(qv.x,v0.y,dot[q][1]); dot[q][1]=fmaf(qv.y,v1.y,dot[q][1]);
                dot[q][1]=fmaf(qv.z,v2.y,dot[q][1]); dot[q][1]=fmaf(qv.w,v3.y,dot[q][1]);
                dot[q][2]=fmaf(qv.x,v0.z,dot[q][2]); dot[q][2]=fmaf(qv.y,v1.z,dot[q][2]);
                dot[q][2]=fmaf(qv.z,v2.z,dot[q][2]); dot[q][2]=fmaf(qv.w,v3.z,dot[q][2]);
                dot[q][3]=fmaf(qv.x,v0.w,dot[q][3]); dot[q][3]=fmaf(qv.y,v1.w,dot[q][3]);
                dot[q][3]=fmaf(qv.z,v2.w,dot[q][3]); dot[q][3]=fmaf(qv.w,v3.w,dot[q][3]);
            }
        }
        #pragma unroll
        for (int k = 0; k < 4; ++k) {
            const int r = rb + 4 * lane + k;
            const float rn  = rnp[r];
            const float rs0 = rsp[r*3+0], rs1 = rsp[r*3+1], rs2 = rsp[r*3+2];
            const float rtv = rtp[r];
            const bool  m   = (mp[r] != 0);
            const float rsn = rs0*rs0 + rs1*rs1 + rs2*rs2;
            #pragma unroll
            for (int q = 0; q < QPW; ++q) {
                float d_x = qn[q] + rn - 2.0f * dot[q][k];
                const float sdot = qs0[q]*rs0 + qs1[q]*rs1 + qs2[q]*rs2;
                float d_s = qsn[q] + rsn - 2.0f * sdot;
                float d_t = rtv - qtv[q];
                if (!m) { d_x = INF; d_s = INF; d_t = INF; }
                if (!(d_t <= 0.f)) d_t = INF;
                const float v = d_x*d_x + d_s*d_s + d_t*d_t;
                const unsigned long long key =
                    ((unsigned long long)__float_as_uint(v) << 32) | (unsigned)r;
                if (q < 2) insert_half(lst01, key, lane, (q & 1) * 32);
                else       insert_half(lst23, key, lane, (q & 1) * 32);
            }
        }
    }

    // ---- emit: 2 passes, 64 lanes each (queries 2p, 2p+1) ----
    #pragma unroll
    for (int p = 0; p < 2; ++p) {
        const unsigned long long myl = p ? lst23 : lst01;
        const int qidx = 2 * p + (lane >> 5);
        const int rsel = (int)(myl & 0xFFFFFFFFull);
        const int gid  = gid0 + qidx;
        const float* qx  = (lane < 32) ? qxp[2*p] : qxp[2*p+1];
        const float qn_  = (lane < 32) ? qn [2*p] : qn [2*p+1];
        const float qs0_ = (lane < 32) ? qs0[2*p] : qs0[2*p+1];
        const float qs1_ = (lane < 32) ? qs1[2*p] : qs1[2*p+1];
        const float qs2_ = (lane < 32) ? qs2[2*p] : qs2[2*p+1];
        const float qsn_ = (lane < 32) ? qsn[2*p] : qsn[2*p+1];
        const float qtv_ = (lane < 32) ? qtv[2*p] : qtv[2*p+1];

        const float4* xr = (const float4*)(x_ctx + ((size_t)b * kNC + rsel) * kDX);
        const float4* qr = (const float4*)qx;
        float dot = 0.f, rn2 = 0.f;
        #pragma unroll
        for (int j = 0; j < 16; ++j) {
            const float4 rv = xr[j];
            const float4 qv = qr[j];
            rn2 = fmaf(rv.x, rv.x, rn2); rn2 = fmaf(rv.y, rv.y, rn2);
            rn2 = fmaf(rv.z, rv.z, rn2); rn2 = fmaf(rv.w, rv.w, rn2);
            dot = fmaf(qv.x, rv.x, dot); dot = fmaf(qv.y, rv.y, dot);
            dot = fmaf(qv.z, rv.z, dot); dot = fmaf(qv.w, rv.w, dot);
        }
        float d_x = qn_ + rn2 - 2.0f * dot;
        const float rs0 = rsp[rsel*3+0], rs1 = rsp[rsel*3+1], rs2 = rsp[rsel*3+2];
        const float rsn = rs0*rs0 + rs1*rs1 + rs2*rs2;
        const float sdot = qs0_*rs0 + qs1_*rs1 + qs2_*rs2;
        float d_s = qsn_ + rsn - 2.0f * sdot;
        const float dt_raw = rtp[rsel] - qtv_;
        const bool  m = (mp[rsel] != 0);
        const bool  causal = m && (dt_raw <= 0.f);

        const float em = causal ? 1.0f : 0.0f;
        const float d_x_out = m ? d_x : kBigFinite;
        const float d_s_out = m ? d_s : kBigFinite;
        const float d_t_out = causal ? dt_raw : kBigFinite;

        const size_t e = (size_t)gid * kK + (size_t)(lane & 31);
        out[e]                = (float)(rsel + b * kNC);
        out[(size_t)kE   + e] = (float)gid;
        out[(size_t)kE*2 + e] = d_x_out;
        out[(size_t)kE*3 + e] = d_s_out;
        out[(size_t)kE*4 + e] = d_t_out;
        out[(size_t)kE*5 + e] = em;
    }
}

// ================= fallback: validated round-4 kernel =================
namespace v2 {
constexpr int QPB = 16, TILE = 64, NT = kNC / TILE;
}
__global__ __launch_bounds__(512)
void knn_edges_v2(const float* __restrict__ x_ctx, const float* __restrict__ s_ctx,
                  const float* __restrict__ t_ctx, const unsigned char* __restrict__ mask_ctx,
                  const float* __restrict__ x_test, const float* __restrict__ s_test,
                  const float* __restrict__ t_test, float* __restrict__ out)
{
    __shared__ float4 xt[2][v2::TILE * 16];
    __shared__ float4 qly[v2::QPB * 16];
    const int tid = threadIdx.x, w = tid >> 6, lane = tid & 63;
    const int qbase = blockIdx.x * v2::QPB;
    if (tid < v2::QPB * 16) {
        const int q = tid >> 4, jj = tid & 15;
        int b_; const float *qx, *qs, *qt;
        resolve_q(qbase + q, x_ctx, s_ctx, t_ctx, x_test, s_test, t_test, b_, qx, qs, qt);
        qly[tid] = ((const float4*)qx)[jj];
    }
    int b;
    { int b_; const float *a, *c, *d;
      resolve_q(qbase, x_ctx, s_ctx, t_ctx, x_test, s_test, t_test, b_, a, c, d); b = b_; }
    const float4* xb4 = (const float4*)x_ctx + (size_t)b * kNC * (kDX / 4);
    const float*  rsp = s_ctx + (size_t)b * kNC * 3;
    const float*  rtp = t_ctx + (size_t)b * kNC;
    const unsigned char* mp = mask_ctx + (size_t)b * kNC;
    const int n0 = w * 128 + lane, n1 = n0 + 64;
    const int r0 = n0 >> 4, j0 = n0 & 15, r1 = n1 >> 4, j1 = n1 & 15;
    const int s0 = (r0 << 4) | (j0 ^ (r0 & 7)), s1 = (r1 << 4) | (j1 ^ (r1 & 7));
    { const float4 g0 = xb4[(size_t)r0*16+j0], g1 = xb4[(size_t)r1*16+j1];
      xt[0][s0] = g0; xt[0][s1] = g1; }
    __syncthreads();
    const int gidA = qbase + 2*w, gidB = gidA + 1;
    int bA, bB; const float *qxA,*qsA,*qtA,*qxB,*qsB,*qtB;
    resolve_q(gidA, x_ctx,s_ctx,t_ctx,x_test,s_test,t_test,bA,qxA,qsA,qtA);
    resolve_q(gidB, x_ctx,s_ctx,t_ctx,x_test,s_test,t_test,bB,qxB,qsB,qtB);
    const float qsA0=qsA[0],qsA1=qsA[1],qsA2=qsA[2],qtvA=qtA[0];
    const float qsB0=qsB[0],qsB1=qsB[1],qsB2=qsB[2],qtvB=qtB[0];
    const float qsnA=qsA0*qsA0+qsA1*qsA1+qsA2*qsA2;
    const float qsnB=qsB0*qsB0+qsB1*qsB1+qsB2*qsB2;
    const float4* qpA = qly + (2*w)*16; const float4* qpB = qly + (2*w+1)*16;
    const float qlA = ((const float*)qpA)[lane]; float qnA = qlA*qlA;
    #pragma unroll
    for (int off=32; off>0; off>>=1) qnA += __shfl_xor(qnA, off, 64);
    const float qlB = ((const float*)qpB)[lane]; float qnB = qlB*qlB;
    #pragma unroll
    for (int off=32; off>0; off>>=1) qnB += __shfl_xor(qnB, off, 64);
    const float INF = __builtin_inff();
    unsigned long long listKey = ~0ull;
    const int lbase = lane << 4, lsw = lane & 7;
    #pragma unroll 2
    for (int t = 0; t < v2::NT; ++t) {
        float4 p0, p1; const bool pre = (t + 1 < v2::NT);
        if (pre) { p0 = xb4[(size_t)(t+1)*1024 + r0*16 + j0];
                   p1 = xb4[(size_t)(t+1)*1024 + r1*16 + j1]; }
        const float4* buf = xt[t & 1];
        float dotA = 0.f, dotB = 0.f, rn = 0.f;
        #pragma unroll
        for (int j = 0; j < 16; ++j) {
            const float4 rv = buf[lbase | (j ^ lsw)];
            const float4 qa = qpA[j]; const float4 qb = qpB[j];
            rn=fmaf(rv.x,rv.x,rn); rn=fmaf(rv.y,rv.y,rn);
            rn=fmaf(rv.z,rv.z,rn); rn=fmaf(rv.w,rv.w,rn);
            dotA=fmaf(qa.x,rv.x,dotA); dotA=fmaf(qa.y,rv.y,dotA);
            dotA=fmaf(qa.z,rv.z,dotA); dotA=fmaf(qa.w,rv.w,dotA);
            dotB=fmaf(qb.x,rv.x,dotB); dotB=fmaf(qb.y,rv.y,dotB);
            dotB=fmaf(qb.z,rv.z,dotB); dotB=fmaf(qb.w,rv.w,dotB);
        }
        const int r = t * v2::TILE + lane;
        const float rs0=rsp[r*3+0], rs1=rsp[r*3+1], rs2=rsp[r*3+2];
        const float rtv=rtp[r]; const bool m=(mp[r]!=0);
        const float rsn=rs0*rs0+rs1*rs1+rs2*rs2;
        {
            float d_x=qnA+rn-2.0f*dotA;
            const float sdot=qsA0*rs0+qsA1*rs1+qsA2*rs2;
            float d_s=qsnA+rsn-2.0f*sdot; float d_t=rtv-qtvA;
            if(!m){d_x=INF;d_s=INF;d_t=INF;} if(!(d_t<=0.f)) d_t=INF;
            const float v=d_x*d_x+d_s*d_s+d_t*d_t;
            insert_half(listKey, ((unsigned long long)__float_as_uint(v)<<32)|(unsigned)r, lane, 0);
        }
        {
            float d_x=qnB+rn-2.0f*dotB;
            const float sdot=qsB0*rs0+qsB1*rs1+qsB2*rs2;
            float d_s=qsnB+rsn-2.0f*sdot; float d_t=rtv-qtvB;
            if(!m){d_x=INF;d_s=INF;d_t=INF;} if(!(d_t<=0.f)) d_t=INF;
            const float v=d_x*d_x+d_s*d_s+d_t*d_t;
            insert_half(listKey, ((unsigned long long)__float_as_uint(v)<<32)|(unsigned)r, lane, 32);
        }
        if (pre) { xt[(t+1)&1][s0]=p0; xt[(t+1)&1][s1]=p1; }
        __syncthreads();
    }
    const int q = lane >> 5, k = lane & 31, gid = gidA + q;
    const int rsel = (int)(listKey & 0xFFFFFFFFull);
    const float qn_ = q?qnB:qnA, qs0_=q?qsB0:qsA0, qs1_=q?qsB1:qsA1,
                qs2_=q?qsB2:qsA2, qsn_=q?qsnB:qsnA, qtv_=q?qtvB:qtvA;
    const float4* qp_ = q ? qpB : qpA;
    float dot=0.f, rn2=0.f;
    #pragma unroll
    for (int j=0;j<16;++j){
        const float4 rv=xb4[(size_t)rsel*16+j]; const float4 qv=qp_[j];
        rn2=fmaf(rv.x,rv.x,rn2); rn2=fmaf(rv.y,rv.y,rn2);
        rn2=fmaf(rv.z,rv.z,rn2); rn2=fmaf(rv.w,rv.w,rn2);
        dot=fmaf(qv.x,rv.x,dot); dot=fmaf(qv.y,rv.y,dot);
        dot=fmaf(qv.z,rv.z,dot); dot=fmaf(qv.w,rv.w,dot);
    }
    float d_x=qn_+rn2-2.0f*dot;
    const float rs0=rsp[rsel*3+0],rs1=rsp[rsel*3+1],rs2=rsp[rsel*3+2];
    const float rsn=rs0*rs0+rs1*rs1+rs2*rs2;
    const float sdot=qs0_*rs0+qs1_*rs1+qs2_*rs2;
    float d_s=qsn_+rsn-2.0f*sdot;
    const float dt_raw=rtp[rsel]-qtv_;
    const bool m=(mp[rsel]!=0), causal=m&&(dt_raw<=0.f);
    const float em=causal?1.0f:0.0f;
    const size_t e=(size_t)gid*kK+(size_t)k;
    out[e]=(float)(rsel+b*kNC); out[(size_t)kE+e]=(float)gid;
    out[(size_t)kE*2+e]=m?d_x:kBigFinite; out[(size_t)kE*3+e]=m?d_s:kBigFinite;
    out[(size_t)kE*4+e]=causal?dt_raw:kBigFinite; out[(size_t)kE*5+e]=em;
}

extern "C" void kernel_launch(void* const* d_in, const int* in_sizes, int n_in,
                              void* d_out, int out_size, void* d_ws, size_t ws_size,
                              hipStream_t stream) {
    (void)in_sizes; (void)n_in; (void)out_size;
    const float* x_ctx = (const float*)d_in[0];
    const float* s_ctx = (const float*)d_in[1];
    const float* t_ctx = (const float*)d_in[2];
    const unsigned char* mask_ctx = (const unsigned char*)d_in[3];
    const float* x_test = (const float*)d_in[4];
    const float* s_test = (const float*)d_in[5];
    const float* t_test = (const float*)d_in[6];

    if (ws_size >= kWsNeed) {
        float* ws = (float*)d_ws;
        prep_transpose<<<dim3(128), dim3(256), 0, stream>>>(x_ctx, ws);
        prep_rn<<<dim3(32), dim3(256), 0, stream>>>(x_ctx, ws);
        knn_v3<<<dim3(2560), dim3(64), 0, stream>>>(
            x_ctx, s_ctx, t_ctx, mask_ctx, x_test, s_test, t_test, ws, (float*)d_out);
    } else {
        knn_edges_v2<<<dim3(kNQ / v2::QPB), dim3(512), 0, stream>>>(
            x_ctx, s_ctx, t_ctx, mask_ctx, x_test, s_test, t_test, (float*)d_out);
    }
}

// Round 6
// 372.272 us; speedup vs baseline: 1.7071x; 1.7071x over previous
//
#include <hip/hip_runtime.h>

namespace {
constexpr int kB  = 2;
constexpr int kNC = 4096;
constexpr int kNT = 1024;
constexpr int kDX = 64;
constexpr int kK  = 32;
constexpr int kNQ = kB * (kNC + kNT);            // 10240
constexpr long long kE = (long long)kNQ * kK;    // 327680
constexpr int QPW  = 4;                          // queries per wave
constexpr int WAVES = 4;                         // waves per block
constexpr int QPB  = WAVES * QPW;                // 16 queries per block
constexpr int TILE = 64;                         // refs per LDS tile
constexpr int NT   = kNC / TILE;                 // 64 tiles
// inf stand-in: must stay finite after bf16 round-trip (FLT_MAX -> bf16 inf)
constexpr float kBigFinite = 1e30f;
}

__device__ __forceinline__ void resolve_q(int gid,
    const float* x_ctx, const float* s_ctx, const float* t_ctx,
    const float* x_test, const float* s_test, const float* t_test,
    int& b, const float*& qx, const float*& qs, const float*& qt)
{
    if (gid < kB * kNC) {
        b  = gid >> 12;
        qx = x_ctx + (size_t)gid * kDX;
        qs = s_ctx + (size_t)gid * 3;
        qt = t_ctx + gid;
    } else {
        const int g2 = gid - kB * kNC;
        b  = g2 >> 10;
        qx = x_test + (size_t)g2 * kDX;
        qs = s_test + (size_t)g2 * 3;
        qt = t_test + g2;
    }
}

// Exact online insert into wave-held sorted ascending top-32 (validated r4/r5).
__device__ __forceinline__ void insert_half(unsigned long long& listKey,
    unsigned long long keyQ, int lane, int base)
{
    const unsigned long long thr = __shfl(listKey, base + 31, 64);
    unsigned long long hb = __ballot(keyQ < thr);
    while (hb) {
        const int srcl = __ffsll((unsigned long long)hb) - 1;
        hb &= hb - 1;
        const unsigned long long K = __shfl(keyQ, srcl, 64);
        const unsigned long long lt = __ballot(listKey < K);
        const unsigned int half = base ? (unsigned int)(lt >> 32)
                                       : (unsigned int)lt;
        const int pos = __popc(half) + base;
        if (pos < base + 32) {
            const unsigned long long up = __shfl_up(listKey, 1, 64);
            if (lane >= base && lane < base + 32) {
                if (lane > pos)       listKey = up;
                else if (lane == pos) listKey = K;
            }
        }
    }
}

__global__ __launch_bounds__(256, 4)
void knn_v4(const float* __restrict__ x_ctx, const float* __restrict__ s_ctx,
            const float* __restrict__ t_ctx, const unsigned char* __restrict__ mask_ctx,
            const float* __restrict__ x_test, const float* __restrict__ s_test,
            const float* __restrict__ t_test, float* __restrict__ out)
{
    __shared__ float4 xt[2][TILE * 16];   // 2 x 16KB double-buffered ref tiles

    const int tid  = threadIdx.x;
    const int lane = tid & 63;
    // force wave index scalar so query pointers become SGPR -> s_load q
    const int w    = __builtin_amdgcn_readfirstlane(tid >> 6);
    const int qbase = blockIdx.x * QPB;
    const int gid0  = qbase + w * QPW;

    // block-uniform batch index
    int b;
    { int b_; const float *a, *c, *d;
      resolve_q(qbase, x_ctx, s_ctx, t_ctx, x_test, s_test, t_test, b_, a, c, d);
      b = b_; }

    const float4* xb4 = (const float4*)x_ctx + (size_t)b * kNC * (kDX / 4);
    const float*  rsp = s_ctx + (size_t)b * kNC * 3;
    const float*  rtp = t_ctx + (size_t)b * kNC;
    const unsigned char* mp = mask_ctx + (size_t)b * kNC;

    // ---- per-wave query setup (4 queries; pointers wave-uniform) ----
    const float* qxp[QPW];
    float qs0[QPW], qs1[QPW], qs2[QPW], qsn[QPW], qtv[QPW], qn[QPW];
    #pragma unroll
    for (int q = 0; q < QPW; ++q) {
        int bb; const float *qx, *qs, *qt;
        resolve_q(gid0 + q, x_ctx, s_ctx, t_ctx, x_test, s_test, t_test,
                  bb, qx, qs, qt);
        qxp[q] = qx;
        qs0[q] = qs[0]; qs1[q] = qs[1]; qs2[q] = qs[2]; qtv[q] = qt[0];
        qsn[q] = qs0[q]*qs0[q] + qs1[q]*qs1[q] + qs2[q]*qs2[q];
        const float ql = qx[lane];
        float s = ql * ql;
        #pragma unroll
        for (int off = 32; off > 0; off >>= 1) s += __shfl_xor(s, off, 64);
        qn[q] = s;
    }

    // staging geometry: 4 float4 per thread per tile, XOR-swizzled LDS dest
    int sg[4], ss[4];
    #pragma unroll
    for (int i = 0; i < 4; ++i) {
        const int n = tid + 256 * i;
        const int r = n >> 4, j = n & 15;
        sg[i] = n;
        ss[i] = (r << 4) | (j ^ (r & 7));
    }
    // prologue: stage tile 0
    #pragma unroll
    for (int i = 0; i < 4; ++i) xt[0][ss[i]] = xb4[sg[i]];
    __syncthreads();

    const int lbase = lane << 4, lsw = lane & 7;
    const float INF = __builtin_inff();
    unsigned long long lst01 = ~0ull, lst23 = ~0ull;

    for (int t = 0; t < NT; ++t) {
        // prefetch next tile into registers (T14: issue early, write late)
        float4 p0, p1, p2, p3;
        const bool pre = (t + 1 < NT);
        if (pre) {
            const size_t nb = (size_t)(t + 1) * 1024;
            p0 = xb4[nb + sg[0]]; p1 = xb4[nb + sg[1]];
            p2 = xb4[nb + sg[2]]; p3 = xb4[nb + sg[3]];
        }
        const float4* buf = xt[t & 1];

        // lane owns ref row `lane`; q operands come from scalar loads
        float dot[QPW] = {0.f, 0.f, 0.f, 0.f};
        float rn = 0.f;
        #pragma unroll
        for (int j = 0; j < 16; ++j) {
            const float4 rv = buf[lbase | (j ^ lsw)];
            rn = fmaf(rv.x, rv.x, rn); rn = fmaf(rv.y, rv.y, rn);
            rn = fmaf(rv.z, rv.z, rn); rn = fmaf(rv.w, rv.w, rn);
            #pragma unroll
            for (int q = 0; q < QPW; ++q) {
                const float4 qv = ((const float4*)qxp[q])[j];   // s_load (uniform)
                dot[q] = fmaf(qv.x, rv.x, dot[q]);
                dot[q] = fmaf(qv.y, rv.y, dot[q]);
                dot[q] = fmaf(qv.z, rv.z, dot[q]);
                dot[q] = fmaf(qv.w, rv.w, dot[q]);
            }
        }

        const int r = t * TILE + lane;
        const float rs0 = rsp[r*3+0], rs1 = rsp[r*3+1], rs2 = rsp[r*3+2];
        const float rtv = rtp[r];
        const bool  m   = (mp[r] != 0);
        const float rsn = rs0*rs0 + rs1*rs1 + rs2*rs2;

        #pragma unroll
        for (int q = 0; q < QPW; ++q) {
            float d_x = qn[q] + rn - 2.0f * dot[q];
            const float sdot = qs0[q]*rs0 + qs1[q]*rs1 + qs2[q]*rs2;
            float d_s = qsn[q] + rsn - 2.0f * sdot;
            float d_t = rtv - qtv[q];
            if (!m) { d_x = INF; d_s = INF; d_t = INF; }
            if (!(d_t <= 0.f)) d_t = INF;
            const float v = d_x*d_x + d_s*d_s + d_t*d_t;
            const unsigned long long key =
                ((unsigned long long)__float_as_uint(v) << 32) | (unsigned)r;
            if (q < 2) insert_half(lst01, key, lane, (q & 1) * 32);
            else       insert_half(lst23, key, lane, (q & 1) * 32);
        }

        if (pre) {
            float4* nbuf = xt[(t + 1) & 1];
            nbuf[ss[0]] = p0; nbuf[ss[1]] = p1;
            nbuf[ss[2]] = p2; nbuf[ss[3]] = p3;
        }
        __syncthreads();
    }

    // ---- emit: 2 passes, 64 lanes each (queries 2p, 2p+1) ----
    #pragma unroll
    for (int p = 0; p < 2; ++p) {
        const unsigned long long myl = p ? lst23 : lst01;
        const int qidx = 2 * p + (lane >> 5);
        const int rsel = (int)(myl & 0xFFFFFFFFull);
        const int gid  = gid0 + qidx;
        const float* qx  = (lane < 32) ? qxp[2*p] : qxp[2*p+1];
        const float qn_  = (lane < 32) ? qn [2*p] : qn [2*p+1];
        const float qs0_ = (lane < 32) ? qs0[2*p] : qs0[2*p+1];
        const float qs1_ = (lane < 32) ? qs1[2*p] : qs1[2*p+1];
        const float qs2_ = (lane < 32) ? qs2[2*p] : qs2[2*p+1];
        const float qsn_ = (lane < 32) ? qsn[2*p] : qsn[2*p+1];
        const float qtv_ = (lane < 32) ? qtv[2*p] : qtv[2*p+1];

        const float4* xr = (const float4*)(x_ctx + ((size_t)b * kNC + rsel) * kDX);
        const float4* qr = (const float4*)qx;
        float dot = 0.f, rn2 = 0.f;
        #pragma unroll
        for (int j = 0; j < 16; ++j) {
            const float4 rv = xr[j];
            const float4 qv = qr[j];
            rn2 = fmaf(rv.x, rv.x, rn2); rn2 = fmaf(rv.y, rv.y, rn2);
            rn2 = fmaf(rv.z, rv.z, rn2); rn2 = fmaf(rv.w, rv.w, rn2);
            dot = fmaf(qv.x, rv.x, dot); dot = fmaf(qv.y, rv.y, dot);
            dot = fmaf(qv.z, rv.z, dot); dot = fmaf(qv.w, rv.w, dot);
        }
        float d_x = qn_ + rn2 - 2.0f * dot;
        const float rs0 = rsp[rsel*3+0], rs1 = rsp[rsel*3+1], rs2 = rsp[rsel*3+2];
        const float rsn = rs0*rs0 + rs1*rs1 + rs2*rs2;
        const float sdot = qs0_*rs0 + qs1_*rs1 + qs2_*rs2;
        float d_s = qsn_ + rsn - 2.0f * sdot;
        const float dt_raw = rtp[rsel] - qtv_;
        const bool  m = (mp[rsel] != 0);
        const bool  causal = m && (dt_raw <= 0.f);

        const float em = causal ? 1.0f : 0.0f;
        const float d_x_out = m ? d_x : kBigFinite;
        const float d_s_out = m ? d_s : kBigFinite;
        const float d_t_out = causal ? dt_raw : kBigFinite;

        const size_t e = (size_t)gid * kK + (size_t)(lane & 31);
        out[e]                = (float)(rsel + b * kNC);
        out[(size_t)kE   + e] = (float)gid;
        out[(size_t)kE*2 + e] = d_x_out;
        out[(size_t)kE*3 + e] = d_s_out;
        out[(size_t)kE*4 + e] = d_t_out;
        out[(size_t)kE*5 + e] = em;
    }
}

extern "C" void kernel_launch(void* const* d_in, const int* in_sizes, int n_in,
                              void* d_out, int out_size, void* d_ws, size_t ws_size,
                              hipStream_t stream) {
    (void)in_sizes; (void)n_in; (void)d_ws; (void)ws_size; (void)out_size;
    const float* x_ctx = (const float*)d_in[0];
    const float* s_ctx = (const float*)d_in[1];
    const float* t_ctx = (const float*)d_in[2];
    const unsigned char* mask_ctx = (const unsigned char*)d_in[3];
    const float* x_test = (const float*)d_in[4];
    const float* s_test = (const float*)d_in[5];
    const float* t_test = (const float*)d_in[6];

    knn_v4<<<dim3(kNQ / QPB), dim3(256), 0, stream>>>(
        x_ctx, s_ctx, t_ctx, mask_ctx, x_test, s_test, t_test, (float*)d_out);
}